// Round 2
// baseline (111.239 us; speedup 1.0000x reference)
//
#include <hip/hip_runtime.h>
#include <hip/hip_fp16.h>

// Problem constants (fixed by the reference)
#define BB 4
#define NN 50000
#define GG 2
#define EE 500000
#define HH 64
#define RR 16

#define CVT (GG * NN * RR / 8)   // 200000 threads: 8 halves per thread per table

// ---------------------------------------------------------------------------
// Kernel A: prep
//  - guh/gvh: fp16 copies of gate_u/gate_v (halves gather bytes; fits L2)
//  - pmB[n]: 4-bit mask of pert_mask[:,n] (values are exactly 0/1)
//  - pw[h] = lin_w @ post_w ; pb[h] = lin_b @ post_w
//  - wts[b,g] = softmax_g(ctx_emb[b] @ mix_w + mix_b)
// ---------------------------------------------------------------------------
__device__ inline uint4 pack8(const float4* s) {
    float4 a = s[0], b = s[1];
    __half2 h0 = __floats2half2_rn(a.x, a.y);
    __half2 h1 = __floats2half2_rn(a.z, a.w);
    __half2 h2 = __floats2half2_rn(b.x, b.y);
    __half2 h3 = __floats2half2_rn(b.z, b.w);
    uint4 o;
    o.x = *(unsigned int*)&h0; o.y = *(unsigned int*)&h1;
    o.z = *(unsigned int*)&h2; o.w = *(unsigned int*)&h3;
    return o;
}

__global__ __launch_bounds__(256) void prep_kernel(
    const float* __restrict__ pert_mask, const float* __restrict__ ctx,
    const float* __restrict__ gu, const float* __restrict__ gv,
    const float* __restrict__ lin_w, const float* __restrict__ lin_b,
    const float* __restrict__ post_w, const float* __restrict__ mix_w,
    const float* __restrict__ mix_b,
    uint4* __restrict__ guh, uint4* __restrict__ gvh,
    unsigned char* __restrict__ pmB,
    float* __restrict__ pw, float* __restrict__ pb, float* __restrict__ wts)
{
    int t = blockIdx.x * 256 + threadIdx.x;
    if (t < CVT) {
        guh[t] = pack8((const float4*)gu + (size_t)t * 2);
        gvh[t] = pack8((const float4*)gv + (size_t)t * 2);
    }
    if (t < NN) {
        unsigned char m =
            (unsigned char)((pert_mask[0*NN + t] != 0.f) ? 1 : 0) |
            (unsigned char)((pert_mask[1*NN + t] != 0.f) ? 2 : 0) |
            (unsigned char)((pert_mask[2*NN + t] != 0.f) ? 4 : 0) |
            (unsigned char)((pert_mask[3*NN + t] != 0.f) ? 8 : 0);
        pmB[t] = m;
    }
    if (blockIdx.x == 0) {
        int tt = threadIdx.x;
        if (tt < HH) {
            float a = 0.f, c = 0.f;
            for (int k = 0; k < HH; ++k) {
                float w = post_w[k*HH + tt];
                a = fmaf(lin_w[k], w, a);
                c = fmaf(lin_b[k], w, c);
            }
            pw[tt] = a; pb[tt] = c;
        } else if (tt < HH + BB) {
            int b = tt - HH;
            float l0 = mix_b[0], l1 = mix_b[1];
            for (int h = 0; h < HH; ++h) {
                float cv = ctx[b*HH + h];
                l0 = fmaf(cv, mix_w[h*GG + 0], l0);
                l1 = fmaf(cv, mix_w[h*GG + 1], l1);
            }
            float m = fmaxf(l0, l1);
            float e0 = __expf(l0 - m), e1 = __expf(l1 - m);
            float inv = 1.f / (e0 + e1);
            wts[b*GG + 0] = e0 * inv;
            wts[b*GG + 1] = e1 * inv;
        }
    }
}

// ---------------------------------------------------------------------------
// Kernel B: per-edge gate + scalar scatter into packed acc[g][n][8]
//  slot 0: s0 += w ; slot 1+b: s1_b += w (mask bit b set)
//  g = blockIdx.x & 1  -> with round-robin block->XCD dispatch, each XCD
//  touches ONE graph's fp16 tables (3.2 MB) -> L2-resident gathers.
// ---------------------------------------------------------------------------
__device__ inline float dot8(uint4 a, uint4 b) {
    const unsigned int* pa = &a.x;
    const unsigned int* pb = &b.x;
    float s = 0.f;
#pragma unroll
    for (int i = 0; i < 4; ++i) {
        float2 fa = __half22float2(*(const __half2*)&pa[i]);
        float2 fb = __half22float2(*(const __half2*)&pb[i]);
        s = fmaf(fa.x, fb.x, s);
        s = fmaf(fa.y, fb.y, s);
    }
    return s;
}

__global__ __launch_bounds__(256) void edge_kernel(
    const int* __restrict__ esrc, const int* __restrict__ edst,
    const float* __restrict__ ewgt, const uint4* __restrict__ guh,
    const uint4* __restrict__ gvh, const unsigned char* __restrict__ pmB,
    float* __restrict__ acc)
{
    int bx = blockIdx.x;
    int g = bx & 1;
    int e = (bx >> 1) * 256 + threadIdx.x;
    if (e >= EE) return;
    size_t ge = (size_t)g * EE + e;
    int s  = __builtin_nontemporal_load(esrc + ge);
    int d  = __builtin_nontemporal_load(edst + ge);
    float w0 = __builtin_nontemporal_load(ewgt + ge);
    size_t ui = ((size_t)g * NN + s) * 2;   // uint4 index: 32B per node
    size_t vi = ((size_t)g * NN + d) * 2;
    uint4 ua = guh[ui], ub = guh[ui + 1];
    uint4 va = gvh[vi], vb = gvh[vi + 1];
    float dot = dot8(ua, va) + dot8(ub, vb);
    float w = w0 / (1.f + __expf(-dot));    // weight * sigmoid(dot)
    unsigned int mb = pmB[s];
    float* base = acc + ((size_t)g * NN + d) * 8;
    atomicAdd(base, w);
    if (mb & 1u) atomicAdd(base + 1, w);
    if (mb & 2u) atomicAdd(base + 2, w);
    if (mb & 4u) atomicAdd(base + 3, w);
    if (mb & 8u) atomicAdd(base + 4, w);
}

// ---------------------------------------------------------------------------
// Kernel C: per-node ReLU + mean, mix weights folded in.
//  thread t owns (b = t>>6, h = t&63); block stages CH packed nodes in LDS.
// ---------------------------------------------------------------------------
#define CH 256

__global__ __launch_bounds__(256) void node_kernel(
    const float4* __restrict__ accv, const float* __restrict__ pw,
    const float* __restrict__ pb, const float* __restrict__ post_b,
    const float* __restrict__ wts, float* __restrict__ out)
{
    int g = blockIdx.y;
    int n0 = blockIdx.x * CH;
    int cnt = min(CH, NN - n0);
    __shared__ float ls[CH][8];
    int t = threadIdx.x;
    for (int i = t; i < cnt * 2; i += 256)
        ((float4*)ls)[i] = accv[((size_t)g * NN + n0) * 2 + i];
    __syncthreads();
    int b = t >> 6, h = t & 63;
    float pwh = pw[h], pbh = pb[h], bias = post_b[h];
    float acc = 0.f;
    for (int i = 0; i < cnt; ++i) {
        float x = fmaf(ls[i][1 + b], pwh, fmaf(ls[i][0], pbh, bias));
        acc += fmaxf(x, 0.f);
    }
    float scale = wts[b * GG + g] * (1.0f / NN);
    atomicAdd(&out[b * HH + h], acc * scale);
}

// ---------------------------------------------------------------------------
extern "C" void kernel_launch(void* const* d_in, const int* in_sizes, int n_in,
                              void* d_out, int out_size, void* d_ws, size_t ws_size,
                              hipStream_t stream) {
    const float* pert_mask = (const float*)d_in[0];
    const float* ctx       = (const float*)d_in[1];
    const int*   esrc      = (const int*)d_in[2];
    const int*   edst      = (const int*)d_in[3];
    const float* ewgt      = (const float*)d_in[4];
    const float* gu        = (const float*)d_in[5];
    const float* gv        = (const float*)d_in[6];
    const float* lin_w     = (const float*)d_in[7];
    const float* lin_b     = (const float*)d_in[8];
    const float* post_w    = (const float*)d_in[9];
    const float* post_b    = (const float*)d_in[10];
    const float* mix_w     = (const float*)d_in[11];
    const float* mix_b     = (const float*)d_in[12];
    float* out = (float*)d_out;

    float* ws = (float*)d_ws;
    float*         acc = ws;                          // G*N*8 = 800000 f (3.2MB)
    uint4*         guh = (uint4*)(ws + 800000);       // G*N*R halves = 3.2MB
    uint4*         gvh = (uint4*)(ws + 1600000);      // 3.2MB
    unsigned char* pmB = (unsigned char*)(ws + 2400000); // N bytes
    float*         pw  = ws + 2412500;                // H
    float*         pb  = pw + HH;                     // H
    float*         wts = pb + HH;                     // B*G

    hipMemsetAsync(acc, 0, (size_t)GG * NN * 8 * sizeof(float), stream);
    hipMemsetAsync(d_out, 0, (size_t)BB * HH * sizeof(float), stream);

    prep_kernel<<<(CVT + 255) / 256, 256, 0, stream>>>(
        pert_mask, ctx, gu, gv, lin_w, lin_b, post_w, mix_w, mix_b,
        guh, gvh, pmB, pw, pb, wts);

    edge_kernel<<<2 * ((EE + 255) / 256), 256, 0, stream>>>(
        esrc, edst, ewgt, guh, gvh, pmB, acc);

    dim3 ng((NN + CH - 1) / CH, GG);
    node_kernel<<<ng, 256, 0, stream>>>((const float4*)acc, pw, pb, post_b, wts, out);
}

// Round 3
// 110.492 us; speedup vs baseline: 1.0068x; 1.0068x over previous
//
#include <hip/hip_runtime.h>
#include <hip/hip_fp16.h>

// Problem constants (fixed by the reference)
#define BB 4
#define NN 50000
#define GG 2
#define EE 500000
#define HH 64
#define RR 16

#define CVT (GG * NN * RR / 8)   // fp16 conversion threads (8 halves/thread/table)

// Binning geometry
#define NT    2048                       // nodes per dst-tile
#define TILES 25                         // ceil(NN / NT)
#define PBLK  256                        // pass-1 blocks per graph
#define EPB   ((EE + PBLK - 1) / PBLK)   // 1954 edges per pass-1 block
#define CAP   144                        // records per (block, tile); mean 78, +7.5 sigma

// ---------------------------------------------------------------------------
// helpers
// ---------------------------------------------------------------------------
__device__ inline uint4 pack8(const float4* s) {
    float4 a = s[0], b = s[1];
    __half2 h0 = __floats2half2_rn(a.x, a.y);
    __half2 h1 = __floats2half2_rn(a.z, a.w);
    __half2 h2 = __floats2half2_rn(b.x, b.y);
    __half2 h3 = __floats2half2_rn(b.z, b.w);
    uint4 o;
    o.x = *(unsigned int*)&h0; o.y = *(unsigned int*)&h1;
    o.z = *(unsigned int*)&h2; o.w = *(unsigned int*)&h3;
    return o;
}

__device__ inline float dot8(uint4 a, uint4 b) {
    const unsigned int* pa = &a.x;
    const unsigned int* pb = &b.x;
    float s = 0.f;
#pragma unroll
    for (int i = 0; i < 4; ++i) {
        float2 fa = __half22float2(*(const __half2*)&pa[i]);
        float2 fb = __half22float2(*(const __half2*)&pb[i]);
        s = fmaf(fa.x, fb.x, s);
        s = fmaf(fa.y, fb.y, s);
    }
    return s;
}

__device__ inline unsigned int f32_to_bf16_rn(float x) {
    unsigned int u = __float_as_uint(x);
    return (u + 0x7FFFu + ((u >> 16) & 1u)) >> 16;   // x >= 0, never NaN here
}

// ---------------------------------------------------------------------------
// Kernel A: prep — fp16 gate tables, pert-mask bitmask, pw/pb, softmax weights
// ---------------------------------------------------------------------------
__global__ __launch_bounds__(256) void prep_kernel(
    const float* __restrict__ pert_mask, const float* __restrict__ ctx,
    const float* __restrict__ gu, const float* __restrict__ gv,
    const float* __restrict__ lin_w, const float* __restrict__ lin_b,
    const float* __restrict__ post_w, const float* __restrict__ mix_w,
    const float* __restrict__ mix_b,
    uint4* __restrict__ guh, uint4* __restrict__ gvh,
    unsigned char* __restrict__ pmB,
    float* __restrict__ pw, float* __restrict__ pb, float* __restrict__ wts)
{
    int t = blockIdx.x * 256 + threadIdx.x;
    if (t < CVT) {
        guh[t] = pack8((const float4*)gu + (size_t)t * 2);
        gvh[t] = pack8((const float4*)gv + (size_t)t * 2);
    }
    if (t < NN) {
        unsigned char m =
            (unsigned char)((pert_mask[0*NN + t] != 0.f) ? 1 : 0) |
            (unsigned char)((pert_mask[1*NN + t] != 0.f) ? 2 : 0) |
            (unsigned char)((pert_mask[2*NN + t] != 0.f) ? 4 : 0) |
            (unsigned char)((pert_mask[3*NN + t] != 0.f) ? 8 : 0);
        pmB[t] = m;
    }
    if (blockIdx.x == 0) {
        int tt = threadIdx.x;
        if (tt < HH) {
            float a = 0.f, c = 0.f;
            for (int k = 0; k < HH; ++k) {
                float w = post_w[k*HH + tt];
                a = fmaf(lin_w[k], w, a);
                c = fmaf(lin_b[k], w, c);
            }
            pw[tt] = a; pb[tt] = c;
        } else if (tt < HH + BB) {
            int b = tt - HH;
            float l0 = mix_b[0], l1 = mix_b[1];
            for (int h = 0; h < HH; ++h) {
                float cv = ctx[b*HH + h];
                l0 = fmaf(cv, mix_w[h*GG + 0], l0);
                l1 = fmaf(cv, mix_w[h*GG + 1], l1);
            }
            float m = fmaxf(l0, l1);
            float e0 = __expf(l0 - m), e1 = __expf(l1 - m);
            float inv = 1.f / (e0 + e1);
            wts[b*GG + 0] = e0 * inv;
            wts[b*GG + 1] = e1 * inv;
        }
    }
}

// ---------------------------------------------------------------------------
// Pass 1: per-edge gate, emit packed record {bf16(w) | mask<<11 | dst_local}
// into bins[g][tile][blk][pos]. Slot from LDS counter: NO global atomics on
// the fast path. g = blockIdx.x & 1 keeps each XCD on one graph's tables.
// ---------------------------------------------------------------------------
__global__ __launch_bounds__(256) void edge_bin_kernel(
    const int* __restrict__ esrc, const int* __restrict__ edst,
    const float* __restrict__ ewgt, const uint4* __restrict__ guh,
    const uint4* __restrict__ gvh, const unsigned char* __restrict__ pmB,
    unsigned int* __restrict__ bins, int* __restrict__ counts,
    float* __restrict__ s0g, float* __restrict__ s1g)
{
    int g   = blockIdx.x & 1;
    int blk = blockIdx.x >> 1;
    __shared__ int lcnt[TILES];
    int tid = threadIdx.x;
    if (tid < TILES) lcnt[tid] = 0;
    __syncthreads();

    int base   = blk * EPB;
    int nEdges = min(EPB, EE - base);
    for (int it = tid; it < nEdges; it += 256) {
        size_t ge = (size_t)g * EE + base + it;
        int   s  = __builtin_nontemporal_load(esrc + ge);
        int   d  = __builtin_nontemporal_load(edst + ge);
        float w0 = __builtin_nontemporal_load(ewgt + ge);
        size_t ui = ((size_t)g * NN + s) * 2;   // 32B fp16 row per node
        size_t vi = ((size_t)g * NN + d) * 2;
        uint4 ua = guh[ui], ub = guh[ui + 1];
        uint4 va = gvh[vi], vb = gvh[vi + 1];
        float dot = dot8(ua, va) + dot8(ub, vb);
        float w = w0 / (1.f + __expf(-dot));     // weight * sigmoid(dot)
        unsigned int mb = pmB[s];

        int tt = d >> 11;          // dst tile
        int dl = d & (NT - 1);     // local dst (11 bits)
        int pos = atomicAdd(&lcnt[tt], 1);
        if (pos < CAP) {
            unsigned int rec = (f32_to_bf16_rn(w) << 16) | (mb << 11) | (unsigned)dl;
            bins[(((size_t)g * TILES + tt) * PBLK + blk) * CAP + pos] = rec;
        } else {
            // exact fallback (statistically never taken; keeps correctness)
            atomicAdd(&s0g[g * NN + d], w);
            if (mb & 1u) atomicAdd(&s1g[((size_t)g * BB + 0) * NN + d], w);
            if (mb & 2u) atomicAdd(&s1g[((size_t)g * BB + 1) * NN + d], w);
            if (mb & 4u) atomicAdd(&s1g[((size_t)g * BB + 2) * NN + d], w);
            if (mb & 8u) atomicAdd(&s1g[((size_t)g * BB + 3) * NN + d], w);
        }
    }
    __syncthreads();
    if (tid < TILES)
        counts[((size_t)g * TILES + tid) * PBLK + blk] = min(lcnt[tid], CAP);
}

// ---------------------------------------------------------------------------
// Pass 2: one block per (tile, g). Replay records into LDS accumulators
// (fast XCD-local ds_add_f32), then write s0/s1 planes once, coalesced.
// ---------------------------------------------------------------------------
#define P2T 512

__global__ __launch_bounds__(P2T) void tile_acc_kernel(
    const unsigned int* __restrict__ bins, const int* __restrict__ counts,
    float* __restrict__ s0g, float* __restrict__ s1g)
{
    int t  = blockIdx.x;
    int g  = blockIdx.y;
    int n0 = t * NT;
    int ncnt = min(NT, NN - n0);
    __shared__ float ls0[NT];
    __shared__ float ls1[BB][NT];
    __shared__ int   lcnts[PBLK];
    int tid = threadIdx.x;

    for (int i = tid; i < ncnt; i += P2T) {
        ls0[i] = s0g[g * NN + n0 + i];   // carries rare fallback contributions
#pragma unroll
        for (int b = 0; b < BB; ++b)
            ls1[b][i] = s1g[((size_t)g * BB + b) * NN + n0 + i];
    }
    for (int i = tid; i < PBLK; i += P2T)
        lcnts[i] = counts[((size_t)g * TILES + t) * PBLK + i];
    __syncthreads();

    int wave = tid >> 6, lane = tid & 63;
    const unsigned int* bbase = bins + ((size_t)g * TILES + t) * PBLK * CAP;
    for (int blk = wave; blk < PBLK; blk += P2T / 64) {
        int cnt = lcnts[blk];
        const unsigned int* rp = bbase + (size_t)blk * CAP;
        for (int i = lane; i < cnt; i += 64) {
            unsigned int r = rp[i];
            float w = __uint_as_float(r & 0xFFFF0000u);
            int d = r & (NT - 1);
            unsigned int mb = (r >> 11) & 15u;
            atomicAdd(&ls0[d], w);
            if (mb & 1u) atomicAdd(&ls1[0][d], w);
            if (mb & 2u) atomicAdd(&ls1[1][d], w);
            if (mb & 4u) atomicAdd(&ls1[2][d], w);
            if (mb & 8u) atomicAdd(&ls1[3][d], w);
        }
    }
    __syncthreads();

    for (int i = tid; i < ncnt; i += P2T) {
        s0g[g * NN + n0 + i] = ls0[i];
#pragma unroll
        for (int b = 0; b < BB; ++b)
            s1g[((size_t)g * BB + b) * NN + n0 + i] = ls1[b][i];
    }
}

// ---------------------------------------------------------------------------
// Node kernel: relu + mean with mix weights folded in (planes layout).
// ---------------------------------------------------------------------------
#define CH 256

__global__ __launch_bounds__(256) void node_kernel(
    const float* __restrict__ s0g, const float* __restrict__ s1g,
    const float* __restrict__ pw, const float* __restrict__ pb,
    const float* __restrict__ post_b, const float* __restrict__ wts,
    float* __restrict__ out)
{
    int g = blockIdx.y;
    int n0 = blockIdx.x * CH;
    int cnt = min(CH, NN - n0);
    __shared__ float a0[CH];
    __shared__ float a1[BB][CH];
    int t = threadIdx.x;
    for (int i = t; i < cnt; i += 256) a0[i] = s0g[g * NN + n0 + i];
#pragma unroll
    for (int b = 0; b < BB; ++b)
        for (int i = t; i < cnt; i += 256)
            a1[b][i] = s1g[((size_t)g * BB + b) * NN + n0 + i];
    __syncthreads();
    int b = t >> 6, h = t & 63;
    float pwh = pw[h], pbh = pb[h], bias = post_b[h];
    float acc = 0.f;
    for (int i = 0; i < cnt; ++i) {
        float x = fmaf(a1[b][i], pwh, fmaf(a0[i], pbh, bias));
        acc += fmaxf(x, 0.f);
    }
    atomicAdd(&out[b * HH + h], acc * wts[b * GG + g] * (1.0f / NN));
}

// ---------------------------------------------------------------------------
extern "C" void kernel_launch(void* const* d_in, const int* in_sizes, int n_in,
                              void* d_out, int out_size, void* d_ws, size_t ws_size,
                              hipStream_t stream) {
    const float* pert_mask = (const float*)d_in[0];
    const float* ctx       = (const float*)d_in[1];
    const int*   esrc      = (const int*)d_in[2];
    const int*   edst      = (const int*)d_in[3];
    const float* ewgt      = (const float*)d_in[4];
    const float* gu        = (const float*)d_in[5];
    const float* gv        = (const float*)d_in[6];
    const float* lin_w     = (const float*)d_in[7];
    const float* lin_b     = (const float*)d_in[8];
    const float* post_w    = (const float*)d_in[9];
    const float* post_b    = (const float*)d_in[10];
    const float* mix_w     = (const float*)d_in[11];
    const float* mix_b     = (const float*)d_in[12];
    float* out = (float*)d_out;

    // workspace layout (float units)
    float* ws = (float*)d_ws;
    float* s0g = ws;                                   // 100000 f
    float* s1g = ws + 100000;                          // 400000 f (contig w/ s0g)
    uint4* guh = (uint4*)(ws + 500000);                // 200000 uint4
    uint4* gvh = guh + 200000;                         // 200000 uint4
    unsigned int* bins = (unsigned int*)(gvh + 200000);        // G*T*PBLK*CAP u32
    int* counts = (int*)(bins + (size_t)GG * TILES * PBLK * CAP); // 12800 int
    unsigned char* pmB = (unsigned char*)(counts + GG * TILES * PBLK); // 50000 B
    float* pw  = (float*)(pmB + 50000);
    float* pb  = pw + HH;
    float* wts = pb + HH;

    // zero accumulators (s0g..s1g contiguous) and output
    hipMemsetAsync(s0g, 0, (size_t)(GG * NN + GG * BB * NN) * sizeof(float), stream);
    hipMemsetAsync(d_out, 0, (size_t)BB * HH * sizeof(float), stream);

    prep_kernel<<<(CVT + 255) / 256, 256, 0, stream>>>(
        pert_mask, ctx, gu, gv, lin_w, lin_b, post_w, mix_w, mix_b,
        guh, gvh, pmB, pw, pb, wts);

    edge_bin_kernel<<<2 * PBLK, 256, 0, stream>>>(
        esrc, edst, ewgt, guh, gvh, pmB, bins, counts, s0g, s1g);

    dim3 tg(TILES, GG);
    tile_acc_kernel<<<tg, P2T, 0, stream>>>(bins, counts, s0g, s1g);

    dim3 ng((NN + CH - 1) / CH, GG);
    node_kernel<<<ng, 256, 0, stream>>>(s0g, s1g, pw, pb, post_b, wts, out);
}

// Round 4
// 78.305 us; speedup vs baseline: 1.4206x; 1.4111x over previous
//
#include <hip/hip_runtime.h>
#include <hip/hip_fp16.h>

// Problem constants (fixed by the reference)
#define BB 4
#define NN 50000
#define GG 2
#define EE 500000
#define HH 64
#define RR 16

#define CVT (GG * NN * RR / 8)   // fp16 conversion threads (8 halves/thread/table)

// Binning geometry
#define NT    2048                       // nodes per dst-tile
#define TILES 25                         // ceil(NN / NT)
#define PBLK  256                        // pass-1 blocks per graph
#define EPB   ((EE + PBLK - 1) / PBLK)   // 1954 edges per pass-1 block
#define CAP   144                        // records per (block, tile); mean 78, +7.5 sigma
#define CCH   8                          // pass-2 chunks per tile
#define CHB   (PBLK / CCH)               // 32 pass-1 bins per chunk

// ---------------------------------------------------------------------------
// helpers
// ---------------------------------------------------------------------------
__device__ inline uint4 pack8(const float4* s) {
    float4 a = s[0], b = s[1];
    __half2 h0 = __floats2half2_rn(a.x, a.y);
    __half2 h1 = __floats2half2_rn(a.z, a.w);
    __half2 h2 = __floats2half2_rn(b.x, b.y);
    __half2 h3 = __floats2half2_rn(b.z, b.w);
    uint4 o;
    o.x = *(unsigned int*)&h0; o.y = *(unsigned int*)&h1;
    o.z = *(unsigned int*)&h2; o.w = *(unsigned int*)&h3;
    return o;
}

__device__ inline float dot8(uint4 a, uint4 b) {
    const unsigned int* pa = &a.x;
    const unsigned int* pb = &b.x;
    float s = 0.f;
#pragma unroll
    for (int i = 0; i < 4; ++i) {
        float2 fa = __half22float2(*(const __half2*)&pa[i]);
        float2 fb = __half22float2(*(const __half2*)&pb[i]);
        s = fmaf(fa.x, fb.x, s);
        s = fmaf(fa.y, fb.y, s);
    }
    return s;
}

__device__ inline unsigned int f32_to_bf16_rn(float x) {
    unsigned int u = __float_as_uint(x);
    return (u + 0x7FFFu + ((u >> 16) & 1u)) >> 16;   // x >= 0, never NaN here
}

// ---------------------------------------------------------------------------
// Kernel A: prep — fp16 gate tables, pert-mask bitmask, pw/pb, softmax weights
// ---------------------------------------------------------------------------
__global__ __launch_bounds__(256) void prep_kernel(
    const float* __restrict__ pert_mask, const float* __restrict__ ctx,
    const float* __restrict__ gu, const float* __restrict__ gv,
    const float* __restrict__ lin_w, const float* __restrict__ lin_b,
    const float* __restrict__ post_w, const float* __restrict__ mix_w,
    const float* __restrict__ mix_b,
    uint4* __restrict__ guh, uint4* __restrict__ gvh,
    unsigned char* __restrict__ pmB,
    float* __restrict__ pw, float* __restrict__ pb, float* __restrict__ wts)
{
    int t = blockIdx.x * 256 + threadIdx.x;
    if (t < CVT) {
        guh[t] = pack8((const float4*)gu + (size_t)t * 2);
        gvh[t] = pack8((const float4*)gv + (size_t)t * 2);
    }
    if (t < NN) {
        unsigned char m =
            (unsigned char)((pert_mask[0*NN + t] != 0.f) ? 1 : 0) |
            (unsigned char)((pert_mask[1*NN + t] != 0.f) ? 2 : 0) |
            (unsigned char)((pert_mask[2*NN + t] != 0.f) ? 4 : 0) |
            (unsigned char)((pert_mask[3*NN + t] != 0.f) ? 8 : 0);
        pmB[t] = m;
    }
    if (blockIdx.x == 0) {
        int tt = threadIdx.x;
        if (tt < HH) {
            float a = 0.f, c = 0.f;
            for (int k = 0; k < HH; ++k) {
                float w = post_w[k*HH + tt];
                a = fmaf(lin_w[k], w, a);
                c = fmaf(lin_b[k], w, c);
            }
            pw[tt] = a; pb[tt] = c;
        } else if (tt < HH + BB) {
            int b = tt - HH;
            float l0 = mix_b[0], l1 = mix_b[1];
            for (int h = 0; h < HH; ++h) {
                float cv = ctx[b*HH + h];
                l0 = fmaf(cv, mix_w[h*GG + 0], l0);
                l1 = fmaf(cv, mix_w[h*GG + 1], l1);
            }
            float m = fmaxf(l0, l1);
            float e0 = __expf(l0 - m), e1 = __expf(l1 - m);
            float inv = 1.f / (e0 + e1);
            wts[b*GG + 0] = e0 * inv;
            wts[b*GG + 1] = e1 * inv;
        }
    }
}

// ---------------------------------------------------------------------------
// Pass 1: per-edge gate, emit packed record {bf16(w) | mask<<11 | dst_local}
// into bins[g][tile][blk][pos]. Slot from LDS counter: NO global atomics on
// the fast path. g = blockIdx.x & 1 keeps each XCD on one graph's tables.
// ---------------------------------------------------------------------------
__global__ __launch_bounds__(256) void edge_bin_kernel(
    const int* __restrict__ esrc, const int* __restrict__ edst,
    const float* __restrict__ ewgt, const uint4* __restrict__ guh,
    const uint4* __restrict__ gvh, const unsigned char* __restrict__ pmB,
    unsigned int* __restrict__ bins, int* __restrict__ counts,
    float* __restrict__ s0g, float* __restrict__ s1g)
{
    int g   = blockIdx.x & 1;
    int blk = blockIdx.x >> 1;
    __shared__ int lcnt[TILES];
    int tid = threadIdx.x;
    if (tid < TILES) lcnt[tid] = 0;
    __syncthreads();

    int base   = blk * EPB;
    int nEdges = min(EPB, EE - base);
    for (int it = tid; it < nEdges; it += 256) {
        size_t ge = (size_t)g * EE + base + it;
        int   s  = __builtin_nontemporal_load(esrc + ge);
        int   d  = __builtin_nontemporal_load(edst + ge);
        float w0 = __builtin_nontemporal_load(ewgt + ge);
        size_t ui = ((size_t)g * NN + s) * 2;   // 32B fp16 row per node
        size_t vi = ((size_t)g * NN + d) * 2;
        uint4 ua = guh[ui], ub = guh[ui + 1];
        uint4 va = gvh[vi], vb = gvh[vi + 1];
        float dot = dot8(ua, va) + dot8(ub, vb);
        float w = w0 / (1.f + __expf(-dot));     // weight * sigmoid(dot)
        unsigned int mb = pmB[s];

        int tt = d >> 11;          // dst tile
        int dl = d & (NT - 1);     // local dst (11 bits)
        int pos = atomicAdd(&lcnt[tt], 1);
        if (pos < CAP) {
            unsigned int rec = (f32_to_bf16_rn(w) << 16) | (mb << 11) | (unsigned)dl;
            bins[(((size_t)g * TILES + tt) * PBLK + blk) * CAP + pos] = rec;
        } else {
            // exact fallback (statistically never taken; keeps correctness)
            atomicAdd(&s0g[g * NN + d], w);
            if (mb & 1u) atomicAdd(&s1g[((size_t)g * BB + 0) * NN + d], w);
            if (mb & 2u) atomicAdd(&s1g[((size_t)g * BB + 1) * NN + d], w);
            if (mb & 4u) atomicAdd(&s1g[((size_t)g * BB + 2) * NN + d], w);
            if (mb & 8u) atomicAdd(&s1g[((size_t)g * BB + 3) * NN + d], w);
        }
    }
    __syncthreads();
    if (tid < TILES)
        counts[((size_t)g * TILES + tid) * PBLK + blk] = min(lcnt[tid], CAP);
}

// ---------------------------------------------------------------------------
// Pass 2: one block per (tile, graph, chunk-of-32-bins). Replay the chunk's
// records into a zeroed LDS accumulator, then write NON-ATOMIC partial
// planes partial[g][c][5][NN] (coalesced). 400 blocks -> latency hidden.
// ---------------------------------------------------------------------------
#define P2T 512

__global__ __launch_bounds__(P2T) void tile_acc_kernel(
    const unsigned int* __restrict__ bins, const int* __restrict__ counts,
    float* __restrict__ partial)
{
    int t = blockIdx.x;      // tile
    int g = blockIdx.y;      // graph
    int c = blockIdx.z;      // chunk
    int n0 = t * NT;
    int ncnt = min(NT, NN - n0);
    __shared__ float ls[5][NT];          // 40 KB
    int tid = threadIdx.x;
    for (int i = tid; i < 5 * NT; i += P2T) ((float*)ls)[i] = 0.f;
    __syncthreads();

    int wv = tid >> 6, ln = tid & 63;
    const unsigned int* bbase = bins + ((size_t)g * TILES + t) * PBLK * CAP;
    const int* cbase = counts + ((size_t)g * TILES + t) * PBLK;
    for (int bI = c * CHB + wv; bI < (c + 1) * CHB; bI += P2T / 64) {
        int cnt = cbase[bI];
        const unsigned int* rp = bbase + (size_t)bI * CAP;
        for (int i = ln; i < cnt; i += 64) {
            unsigned int r = rp[i];
            float w = __uint_as_float(r & 0xFFFF0000u);
            int d = r & (NT - 1);
            unsigned int mb = (r >> 11) & 15u;
            atomicAdd(&ls[0][d], w);
            if (mb & 1u) atomicAdd(&ls[1][d], w);
            if (mb & 2u) atomicAdd(&ls[2][d], w);
            if (mb & 4u) atomicAdd(&ls[3][d], w);
            if (mb & 8u) atomicAdd(&ls[4][d], w);
        }
    }
    __syncthreads();

    float* pbase = partial + (((size_t)g * CCH + c) * 5) * NN + n0;
#pragma unroll
    for (int p = 0; p < 5; ++p)
        for (int i = tid; i < ncnt; i += P2T)
            pbase[(size_t)p * NN + i] = ls[p][i];
}

// ---------------------------------------------------------------------------
// Node kernel: sum chunk partials + fallback planes, then relu + mean with
// mix weights folded in. Thread t owns node i = t of the block's 256-window
// for staging, then (b,h) = (t>>6, t&63) for the reduction.
// ---------------------------------------------------------------------------
#define CH 256

__global__ __launch_bounds__(256) void node_kernel(
    const float* __restrict__ partial, const float* __restrict__ s0g,
    const float* __restrict__ s1g, const float* __restrict__ pw,
    const float* __restrict__ pb, const float* __restrict__ post_b,
    const float* __restrict__ wts, float* __restrict__ out)
{
    int g = blockIdx.y;
    int n0 = blockIdx.x * CH;
    int cnt = min(CH, NN - n0);
    __shared__ float a[5][CH];
    int t = threadIdx.x;
    if (t < cnt) {
        float v0 = s0g[g * NN + n0 + t];
        float v1 = s1g[((size_t)g * BB + 0) * NN + n0 + t];
        float v2 = s1g[((size_t)g * BB + 1) * NN + n0 + t];
        float v3 = s1g[((size_t)g * BB + 2) * NN + n0 + t];
        float v4 = s1g[((size_t)g * BB + 3) * NN + n0 + t];
#pragma unroll
        for (int c = 0; c < CCH; ++c) {
            const float* pp = partial + (((size_t)g * CCH + c) * 5) * NN + n0 + t;
            v0 += pp[0];
            v1 += pp[(size_t)1 * NN];
            v2 += pp[(size_t)2 * NN];
            v3 += pp[(size_t)3 * NN];
            v4 += pp[(size_t)4 * NN];
        }
        a[0][t] = v0; a[1][t] = v1; a[2][t] = v2; a[3][t] = v3; a[4][t] = v4;
    }
    __syncthreads();
    int b = t >> 6, h = t & 63;
    float pwh = pw[h], pbh = pb[h], bias = post_b[h];
    float acc = 0.f;
    for (int i = 0; i < cnt; ++i) {
        float x = fmaf(a[1 + b][i], pwh, fmaf(a[0][i], pbh, bias));
        acc += fmaxf(x, 0.f);
    }
    atomicAdd(&out[b * HH + h], acc * wts[b * GG + g] * (1.0f / NN));
}

// ---------------------------------------------------------------------------
extern "C" void kernel_launch(void* const* d_in, const int* in_sizes, int n_in,
                              void* d_out, int out_size, void* d_ws, size_t ws_size,
                              hipStream_t stream) {
    const float* pert_mask = (const float*)d_in[0];
    const float* ctx       = (const float*)d_in[1];
    const int*   esrc      = (const int*)d_in[2];
    const int*   edst      = (const int*)d_in[3];
    const float* ewgt      = (const float*)d_in[4];
    const float* gu        = (const float*)d_in[5];
    const float* gv        = (const float*)d_in[6];
    const float* lin_w     = (const float*)d_in[7];
    const float* lin_b     = (const float*)d_in[8];
    const float* post_w    = (const float*)d_in[9];
    const float* post_b    = (const float*)d_in[10];
    const float* mix_w     = (const float*)d_in[11];
    const float* mix_b     = (const float*)d_in[12];
    float* out = (float*)d_out;

    // workspace layout (float units)
    float* ws = (float*)d_ws;
    float* s0g = ws;                                   // 100000 f
    float* s1g = ws + 100000;                          // 400000 f (contig w/ s0g)
    uint4* guh = (uint4*)(ws + 500000);                // 200000 uint4 = 800000 f
    uint4* gvh = guh + 200000;                         // 800000 f
    unsigned int* bins = (unsigned int*)(gvh + 200000);            // 1,843,200 u32
    int* counts = (int*)(bins + (size_t)GG * TILES * PBLK * CAP);  // 12800 int
    unsigned char* pmB = (unsigned char*)(counts + GG * TILES * PBLK); // 50000 B
    float* pw  = (float*)(pmB + 50000);                // 64 f
    float* pb  = pw + HH;                              // 64 f
    float* wts = pb + HH;                              // 8 f
    float* partial = wts + 8 + 4;                      // G*CCH*5*NN = 4,000,000 f

    // zero fallback accumulators (s0g..s1g contiguous) and output
    hipMemsetAsync(s0g, 0, (size_t)(GG * NN + GG * BB * NN) * sizeof(float), stream);
    hipMemsetAsync(d_out, 0, (size_t)BB * HH * sizeof(float), stream);

    prep_kernel<<<(CVT + 255) / 256, 256, 0, stream>>>(
        pert_mask, ctx, gu, gv, lin_w, lin_b, post_w, mix_w, mix_b,
        guh, gvh, pmB, pw, pb, wts);

    edge_bin_kernel<<<2 * PBLK, 256, 0, stream>>>(
        esrc, edst, ewgt, guh, gvh, pmB, bins, counts, s0g, s1g);

    dim3 tg(TILES, GG, CCH);
    tile_acc_kernel<<<tg, P2T, 0, stream>>>(bins, counts, partial);

    dim3 ng((NN + CH - 1) / CH, GG);
    node_kernel<<<ng, 256, 0, stream>>>(partial, s0g, s1g, pw, pb, post_b, wts, out);
}